// Round 1
// baseline (986.674 us; speedup 1.0000x reference)
//
#include <hip/hip_runtime.h>

#define CRF_B 256
#define CRF_L 1024
#define CRF_T 128

__global__ void zero_out_kernel(float* out) { out[0] = 0.0f; }

// gold score: one thread per (b,l); subtract from out
__global__ __launch_bounds__(256) void gold_kernel(
    const float* __restrict__ trans, const float* __restrict__ feats,
    const int* __restrict__ mask, const int* __restrict__ tags,
    float* __restrict__ out)
{
    int idx = blockIdx.x * 256 + threadIdx.x;   // idx = b*L + l
    float val = 0.0f;
    if (idx < CRF_B * CRF_L) {
        if (mask[idx] != 0) {
            int l = idx & (CRF_L - 1);
            int tg = tags[idx];
            val = feats[(size_t)idx * CRF_T + tg];
            if (l > 0) val += trans[tags[idx - 1] * CRF_T + tg];
        }
    }
    for (int off = 32; off > 0; off >>= 1) val += __shfl_down(val, off, 64);
    __shared__ float s_w[4];
    int lane = threadIdx.x & 63, w = threadIdx.x >> 6;
    if (lane == 0) s_w[w] = val;
    __syncthreads();
    if (threadIdx.x == 0) {
        atomicAdd(out, -(s_w[0] + s_w[1] + s_w[2] + s_w[3]));
    }
}

// forward scan: one workgroup (256 threads) per batch.
// E = exp(trans) cached in registers: thread (j=t&127, h=t>>7) holds
// E[h*64 + k][j], k=0..63.
__global__ __launch_bounds__(256) void forward_kernel(
    const float* __restrict__ trans, const float* __restrict__ feats,
    const int* __restrict__ mask, float* __restrict__ out)
{
    const int b    = blockIdx.x;
    const int t    = threadIdx.x;
    const int j    = t & (CRF_T - 1);
    const int h    = t >> 7;           // which half of i-range
    const int lane = t & 63;
    const int w    = t >> 6;

    __shared__ float4 s_e4[CRF_T / 4];       // e = exp(p - m), 128 floats
    __shared__ float  s_part[CRF_T * 2];     // partial sums [j][h]
    __shared__ float  s_red[4];
    __shared__ int    s_len;

    float* s_e = (float*)s_e4;

    // ---- per-batch length (mask is a monotone prefix) ----
    if (t == 0) s_len = 0;
    __syncthreads();
    {
        int cnt = 0;
        for (int l = t; l < CRF_L; l += 256) cnt += (mask[b * CRF_L + l] != 0);
        for (int off = 32; off > 0; off >>= 1) cnt += __shfl_down(cnt, off, 64);
        if (lane == 0) atomicAdd(&s_len, cnt);
    }

    // ---- E into registers (one-time) ----
    float Ereg[64];
#pragma unroll
    for (int k = 0; k < 64; ++k)
        Ereg[k] = __expf(trans[(h * 64 + k) * CRF_T + j]);

    __syncthreads();
    const int len = s_len;

    const float* fb = feats + (size_t)b * CRF_L * CRF_T;

    // partition p held by threads t < 128 (p for tag index t)
    float p = 0.0f, f0 = 0.0f, f1 = 0.0f;
    if (t < CRF_T) {
        p  = fb[0 * CRF_T + t];
        f0 = fb[1 * CRF_T + t];
        f1 = fb[2 * CRF_T + t];
    }

    for (int l = 1; l < len; ++l) {
        // ---- m = max_i p[i] ----
        float v = (t < CRF_T) ? p : -3.0e38f;
        for (int off = 32; off > 0; off >>= 1) v = fmaxf(v, __shfl_xor(v, off, 64));
        if (lane == 0) s_red[w] = v;
        __syncthreads();                                       // A
        const float m = fmaxf(fmaxf(s_red[0], s_red[1]), fmaxf(s_red[2], s_red[3]));

        // ---- e = exp(p - m) ----
        if (t < CRF_T) s_e[t] = __expf(p - m);
        __syncthreads();                                       // B

        // ---- partial matvec: acc = sum_{k} e[h*64+k] * E[h*64+k][j] ----
        float a0 = 0.f, a1 = 0.f, a2 = 0.f, a3 = 0.f;
        const float4* e4 = (const float4*)s_e + h * 16;
#pragma unroll
        for (int kq = 0; kq < 16; ++kq) {
            float4 q = e4[kq];                 // wave-uniform broadcast read
            a0 = fmaf(q.x, Ereg[kq * 4 + 0], a0);
            a1 = fmaf(q.y, Ereg[kq * 4 + 1], a1);
            a2 = fmaf(q.z, Ereg[kq * 4 + 2], a2);
            a3 = fmaf(q.w, Ereg[kq * 4 + 3], a3);
        }
        s_part[j * 2 + h] = (a0 + a1) + (a2 + a3);
        __syncthreads();                                       // C

        // ---- p update + feats prefetch ----
        if (t < CRF_T) {
            float s = s_part[t * 2 + 0] + s_part[t * 2 + 1];
            p = f0 + m + __logf(s);
            f0 = f1;
            int lp = (l + 2 < CRF_L) ? (l + 2) : (CRF_L - 1);
            f1 = fb[lp * CRF_T + t];
        }
    }

    // ---- final logsumexp over p, accumulate into out ----
    float v = (t < CRF_T) ? p : -3.0e38f;
    for (int off = 32; off > 0; off >>= 1) v = fmaxf(v, __shfl_xor(v, off, 64));
    if (lane == 0) s_red[w] = v;
    __syncthreads();
    const float m = fmaxf(fmaxf(s_red[0], s_red[1]), fmaxf(s_red[2], s_red[3]));
    float ev = (t < CRF_T) ? __expf(p - m) : 0.0f;
    for (int off = 32; off > 0; off >>= 1) ev += __shfl_xor(ev, off, 64);
    if (lane == 0) s_part[w] = ev;
    __syncthreads();
    if (t == 0) {
        atomicAdd(out, m + __logf(s_part[0] + s_part[1] + s_part[2] + s_part[3]));
    }
}

extern "C" void kernel_launch(void* const* d_in, const int* in_sizes, int n_in,
                              void* d_out, int out_size, void* d_ws, size_t ws_size,
                              hipStream_t stream) {
    const float* trans = (const float*)d_in[0];
    const float* feats = (const float*)d_in[1];
    const int*   mask  = (const int*)d_in[2];
    const int*   tags  = (const int*)d_in[3];
    float*       out   = (float*)d_out;

    hipLaunchKernelGGL(zero_out_kernel, dim3(1), dim3(1), 0, stream, out);
    hipLaunchKernelGGL(gold_kernel, dim3((CRF_B * CRF_L) / 256), dim3(256), 0, stream,
                       trans, feats, mask, tags, out);
    hipLaunchKernelGGL(forward_kernel, dim3(CRF_B), dim3(256), 0, stream,
                       trans, feats, mask, out);
}

// Round 2
// 792.594 us; speedup vs baseline: 1.2449x; 1.2449x over previous
//
#include <hip/hip_runtime.h>

#define CRF_B 256
#define CRF_L 1024
#define CRF_T 128

__global__ void zero_out_kernel(float* out) { out[0] = 0.0f; }

// One workgroup (256 threads = 4 waves) per batch.
// Wave w owns tags j in [32w, 32w+32). Lane layout: lp = lane&31 selects j,
// half = lane>>5 selects i-range half. E cached in registers:
// lane holds E[64*half + k][j], k = 0..63.
// One barrier per step; running max is 2-step stale (bounded drift, safe in fp32).
__global__ __launch_bounds__(256) void forward_kernel(
    const float* __restrict__ trans, const float* __restrict__ feats,
    const int* __restrict__ mask, const int* __restrict__ tags,
    float* __restrict__ out)
{
    const int b    = blockIdx.x;
    const int t    = threadIdx.x;
    const int w    = t >> 6;
    const int lane = t & 63;
    const int lp   = lane & 31;
    const int half = lane >> 5;
    const int j    = w * 32 + lp;

    __shared__ float s_e[2][CRF_T];    // exp(p - m), double-buffered by step parity
    __shared__ float s_red[2][4];      // per-wave maxes, double-buffered
    __shared__ float s_gold;
    __shared__ int   s_len;

    if (t == 0) { s_len = 0; s_gold = 0.0f; }
    __syncthreads();

    // ---- per-batch length + gold score (merged single pass over mask) ----
    {
        int   cnt  = 0;
        float gsum = 0.0f;
        const int base = b * CRF_L;
        for (int l = t; l < CRF_L; l += 256) {
            if (mask[base + l] != 0) {
                cnt++;
                int tg = tags[base + l];
                float gv = feats[(size_t)(base + l) * CRF_T + tg];
                if (l > 0) gv += trans[tags[base + l - 1] * CRF_T + tg];
                gsum += gv;
            }
        }
        for (int off = 32; off > 0; off >>= 1) {
            cnt  += __shfl_down(cnt, off, 64);
            gsum += __shfl_down(gsum, off, 64);
        }
        if (lane == 0) { atomicAdd(&s_len, cnt); atomicAdd(&s_gold, gsum); }
    }

    // ---- E = exp(trans) into registers (one-time) ----
    float Ereg[64];
#pragma unroll
    for (int k = 0; k < 64; ++k)
        Ereg[k] = __expf(trans[(half * 64 + k) * CRF_T + j]);

    const float* fb = feats + (size_t)b * CRF_L * CRF_T;
    float p  = fb[j];                 // p_0 (both halves identical)
    float f0 = fb[CRF_T + j];         // f_1
    float f1 = fb[2 * CRF_T + j];     // f_2

    // ---- init: wave-max(p0) into both s_red slots ----
    {
        float v = p;
        v = fmaxf(v, __shfl_xor(v, 1, 64));
        v = fmaxf(v, __shfl_xor(v, 2, 64));
        v = fmaxf(v, __shfl_xor(v, 4, 64));
        v = fmaxf(v, __shfl_xor(v, 8, 64));
        v = fmaxf(v, __shfl_xor(v, 16, 64));
        if (lane == 0) { s_red[0][w] = v; s_red[1][w] = v; }
    }
    __syncthreads();
    const int len = s_len;
    float m = fmaxf(fmaxf(s_red[1][0], s_red[1][1]), fmaxf(s_red[1][2], s_red[1][3]));

    for (int l = 1; l < len; ++l) {
        const int sl = l & 1;

        // e = exp(p - m_stale); half 0 publishes (both halves hold identical p)
        float e = __expf(p - m);
        if (half == 0) s_e[sl][j] = e;
        __syncthreads();                               // the ONE barrier per step

        // max written last step (or init) — becomes m at the END of this step
        float m_next = fmaxf(fmaxf(s_red[sl][0], s_red[sl][1]),
                             fmaxf(s_red[sl][2], s_red[sl][3]));

        // matvec partial over own i-half: acc_j = sum_k e[64h+k] * E[64h+k][j]
        const float4* e4 = (const float4*)(&s_e[sl][half * 64]);
        float a0 = 0.f, a1 = 0.f, a2 = 0.f, a3 = 0.f;
#pragma unroll
        for (int kq = 0; kq < 16; ++kq) {
            float4 q = e4[kq];                          // group-uniform broadcast
            a0 = fmaf(q.x, Ereg[4 * kq + 0], a0);
            a1 = fmaf(q.y, Ereg[4 * kq + 1], a1);
            a2 = fmaf(q.z, Ereg[4 * kq + 2], a2);
            a3 = fmaf(q.w, Ereg[4 * kq + 3], a3);
        }
        float acc = (a0 + a1) + (a2 + a3);
        acc += __shfl_xor(acc, 32, 64);                 // combine i-halves

        // lagged wave-max of current p (overlaps matvec; consumed next step)
        {
            float vmax = p;
            vmax = fmaxf(vmax, __shfl_xor(vmax, 1, 64));
            vmax = fmaxf(vmax, __shfl_xor(vmax, 2, 64));
            vmax = fmaxf(vmax, __shfl_xor(vmax, 4, 64));
            vmax = fmaxf(vmax, __shfl_xor(vmax, 8, 64));
            vmax = fmaxf(vmax, __shfl_xor(vmax, 16, 64));
            if (lane == 0) s_red[sl ^ 1][w] = vmax;
        }

        // p update + feats prefetch (2 deep)
        p  = f0 + m + __logf(acc);
        m  = m_next;
        f0 = f1;
        int lnext = (l + 2 < CRF_L) ? (l + 2) : (CRF_L - 1);
        f1 = fb[(size_t)lnext * CRF_T + j];
    }

    // ---- final exact logsumexp over p ----
    {
        float v = p;
        v = fmaxf(v, __shfl_xor(v, 1, 64));
        v = fmaxf(v, __shfl_xor(v, 2, 64));
        v = fmaxf(v, __shfl_xor(v, 4, 64));
        v = fmaxf(v, __shfl_xor(v, 8, 64));
        v = fmaxf(v, __shfl_xor(v, 16, 64));
        if (lane == 0) s_red[0][w] = v;
        __syncthreads();
        float mm = fmaxf(fmaxf(s_red[0][0], s_red[0][1]),
                         fmaxf(s_red[0][2], s_red[0][3]));
        float ev = (half == 0) ? __expf(p - mm) : 0.0f;
        ev += __shfl_xor(ev, 1, 64);
        ev += __shfl_xor(ev, 2, 64);
        ev += __shfl_xor(ev, 4, 64);
        ev += __shfl_xor(ev, 8, 64);
        ev += __shfl_xor(ev, 16, 64);
        ev += __shfl_xor(ev, 32, 64);
        if (lane == 0) s_e[0][w] = ev;
        __syncthreads();
        if (t == 0) {
            float tot = s_e[0][0] + s_e[0][1] + s_e[0][2] + s_e[0][3];
            atomicAdd(out, mm + __logf(tot) - s_gold);
        }
    }
}

extern "C" void kernel_launch(void* const* d_in, const int* in_sizes, int n_in,
                              void* d_out, int out_size, void* d_ws, size_t ws_size,
                              hipStream_t stream) {
    const float* trans = (const float*)d_in[0];
    const float* feats = (const float*)d_in[1];
    const int*   mask  = (const int*)d_in[2];
    const int*   tags  = (const int*)d_in[3];
    float*       out   = (float*)d_out;

    hipLaunchKernelGGL(zero_out_kernel, dim3(1), dim3(1), 0, stream, out);
    hipLaunchKernelGGL(forward_kernel, dim3(CRF_B), dim3(256), 0, stream,
                       trans, feats, mask, tags, out);
}

// Round 3
// 643.705 us; speedup vs baseline: 1.5328x; 1.2313x over previous
//
#include <hip/hip_runtime.h>

#define CRF_B 256
#define CRF_L 1024
#define CRF_T 128

typedef __attribute__((ext_vector_type(8)))  short bf16x8;
typedef __attribute__((ext_vector_type(16))) float f32x16;

__global__ void zero_out_kernel(float* out) { out[0] = 0.0f; }

static __device__ __forceinline__ unsigned short f2bf(float x) {
    union { float f; unsigned u; } v; v.f = x;
    unsigned r = v.u + 0x7FFFu + ((v.u >> 16) & 1u);   // round-to-nearest-even
    return (unsigned short)(r >> 16);
}

// One workgroup (256 threads = 4 waves) per batch. Wave w owns cols
// [32w, 32w+32). Matvec s[j] = sum_k e[k]*E[k][j] done with
// v_mfma_f32_32x32x16_bf16: B = E fragments (preloaded, 8 k-tiles),
// A = e broadcast (every lane reads the same 16B per k-tile, so all A rows
// equal e and every lane's acc[0] holds s[lane&31] — halves duplicate free).
// One barrier per step; max is 2-step stale (bounded drift; proven scheme).
__global__ __launch_bounds__(256) void forward_kernel(
    const float* __restrict__ trans, const float* __restrict__ feats,
    const int* __restrict__ mask, const int* __restrict__ tags,
    float* __restrict__ out)
{
    const int b    = blockIdx.x;
    const int t    = threadIdx.x;
    const int w    = t >> 6;
    const int lane = t & 63;
    const int col  = lane & 31;
    const int h    = lane >> 5;
    const int j    = w * 32 + col;

    __shared__ __align__(16) unsigned short s_e[2][CRF_T];  // e in bf16, parity dbuf
    __shared__ float4 s_red4[2];                            // per-wave maxes
    __shared__ float  s_fin[4];
    __shared__ float  s_gold;
    __shared__ int    s_len;

    if (t == 0) { s_len = 0; s_gold = 0.0f; }
    __syncthreads();

    // ---- per-batch length + gold score (single merged pass) ----
    {
        int cnt = 0; float gsum = 0.0f;
        const int base = b * CRF_L;
        for (int l = t; l < CRF_L; l += 256) {
            if (mask[base + l] != 0) {
                cnt++;
                int tg = tags[base + l];
                float gv = feats[(size_t)(base + l) * CRF_T + tg];
                if (l > 0) gv += trans[tags[base + l - 1] * CRF_T + tg];
                gsum += gv;
            }
        }
        for (int off = 32; off > 0; off >>= 1) {
            cnt  += __shfl_down(cnt, off, 64);
            gsum += __shfl_down(gsum, off, 64);
        }
        if (lane == 0) { atomicAdd(&s_len, cnt); atomicAdd(&s_gold, gsum); }
    }

    // ---- E = exp(trans) as bf16 B-fragments (one-time) ----
    // lane holds E[16*kt + 8*h + e][j], e = 0..7  (A/B share this k-map,
    // so any bijective k-layout assumption cancels between operands)
    bf16x8 Efrag[8];
#pragma unroll
    for (int kt = 0; kt < 8; ++kt) {
#pragma unroll
        for (int e = 0; e < 8; ++e) {
            int k = 16 * kt + 8 * h + e;
            Efrag[kt][e] = (short)f2bf(__expf(trans[k * CRF_T + j]));
        }
    }

    const float* fb = feats + (size_t)b * CRF_L * CRF_T;
    float p  = fb[j];                 // p_0 (duplicated across halves)
    float f0 = fb[CRF_T + j];
    float f1 = fb[2 * CRF_T + j];

    // init: wave max of p0 into both parity slots
    {
        float v = p;
        v = fmaxf(v, __shfl_xor(v, 1, 64));
        v = fmaxf(v, __shfl_xor(v, 2, 64));
        v = fmaxf(v, __shfl_xor(v, 4, 64));
        v = fmaxf(v, __shfl_xor(v, 8, 64));
        v = fmaxf(v, __shfl_xor(v, 16, 64));
        if (lane == 0) { ((float*)&s_red4[0])[w] = v; ((float*)&s_red4[1])[w] = v; }
    }
    __syncthreads();
    const int len = s_len;
    float4 r0 = s_red4[1];
    float m = fmaxf(fmaxf(r0.x, r0.y), fmaxf(r0.z, r0.w));

    for (int l = 1; l < len; ++l) {
        const int sl = l & 1;

        // e = exp(p - m_stale); half 0 publishes its wave's 32 cols
        float ev = __expf(p - m);
        if (h == 0) s_e[sl][j] = f2bf(ev);
        __syncthreads();                       // the ONE barrier per step

        // A fragments: broadcast 16B per k-tile (same addr per 32-lane group)
        bf16x8 A0 = *(const bf16x8*)&s_e[sl][16 * 0 + 8 * h];
        bf16x8 A1 = *(const bf16x8*)&s_e[sl][16 * 1 + 8 * h];
        bf16x8 A2 = *(const bf16x8*)&s_e[sl][16 * 2 + 8 * h];
        bf16x8 A3 = *(const bf16x8*)&s_e[sl][16 * 3 + 8 * h];
        bf16x8 A4 = *(const bf16x8*)&s_e[sl][16 * 4 + 8 * h];
        bf16x8 A5 = *(const bf16x8*)&s_e[sl][16 * 5 + 8 * h];
        bf16x8 A6 = *(const bf16x8*)&s_e[sl][16 * 6 + 8 * h];
        bf16x8 A7 = *(const bf16x8*)&s_e[sl][16 * 7 + 8 * h];

        f32x16 ac0 = {0.0f}, ac1 = {0.0f}, ac2 = {0.0f}, ac3 = {0.0f};
        ac0 = __builtin_amdgcn_mfma_f32_32x32x16_bf16(A0, Efrag[0], ac0, 0, 0, 0);
        ac1 = __builtin_amdgcn_mfma_f32_32x32x16_bf16(A1, Efrag[1], ac1, 0, 0, 0);
        ac2 = __builtin_amdgcn_mfma_f32_32x32x16_bf16(A2, Efrag[2], ac2, 0, 0, 0);
        ac3 = __builtin_amdgcn_mfma_f32_32x32x16_bf16(A3, Efrag[3], ac3, 0, 0, 0);
        ac0 = __builtin_amdgcn_mfma_f32_32x32x16_bf16(A4, Efrag[4], ac0, 0, 0, 0);
        ac1 = __builtin_amdgcn_mfma_f32_32x32x16_bf16(A5, Efrag[5], ac1, 0, 0, 0);
        ac2 = __builtin_amdgcn_mfma_f32_32x32x16_bf16(A6, Efrag[6], ac2, 0, 0, 0);
        ac3 = __builtin_amdgcn_mfma_f32_32x32x16_bf16(A7, Efrag[7], ac3, 0, 0, 0);

        // stale-max bookkeeping (off the critical path)
        float4 rr = s_red4[sl];
        float m_next = fmaxf(fmaxf(rr.x, rr.y), fmaxf(rr.z, rr.w));
        {
            float vmax = p;
            vmax = fmaxf(vmax, __shfl_xor(vmax, 1, 64));
            vmax = fmaxf(vmax, __shfl_xor(vmax, 2, 64));
            vmax = fmaxf(vmax, __shfl_xor(vmax, 4, 64));
            vmax = fmaxf(vmax, __shfl_xor(vmax, 8, 64));
            vmax = fmaxf(vmax, __shfl_xor(vmax, 16, 64));
            if (lane == 0) ((float*)&s_red4[sl ^ 1])[w] = vmax;
        }

        // p update + feats prefetch (row 0 of D lives in acc[0] of every lane)
        float s = (ac0[0] + ac1[0]) + (ac2[0] + ac3[0]);
        p = f0 + m + __logf(s);
        m = m_next;
        f0 = f1;
        int ln = (l + 2 < CRF_L) ? (l + 2) : (CRF_L - 1);
        f1 = fb[(size_t)ln * CRF_T + j];
    }

    // ---- final exact logsumexp over p ----
    {
        float v = p;
        v = fmaxf(v, __shfl_xor(v, 1, 64));
        v = fmaxf(v, __shfl_xor(v, 2, 64));
        v = fmaxf(v, __shfl_xor(v, 4, 64));
        v = fmaxf(v, __shfl_xor(v, 8, 64));
        v = fmaxf(v, __shfl_xor(v, 16, 64));
        if (lane == 0) ((float*)&s_red4[0])[w] = v;
        __syncthreads();
        float4 rr = s_red4[0];
        float mm = fmaxf(fmaxf(rr.x, rr.y), fmaxf(rr.z, rr.w));
        float ev = (h == 0) ? __expf(p - mm) : 0.0f;
        ev += __shfl_xor(ev, 1, 64);
        ev += __shfl_xor(ev, 2, 64);
        ev += __shfl_xor(ev, 4, 64);
        ev += __shfl_xor(ev, 8, 64);
        ev += __shfl_xor(ev, 16, 64);
        ev += __shfl_xor(ev, 32, 64);
        if (lane == 0) s_fin[w] = ev;
        __syncthreads();
        if (t == 0) {
            float tot = s_fin[0] + s_fin[1] + s_fin[2] + s_fin[3];
            atomicAdd(out, mm + __logf(tot) - s_gold);
        }
    }
}

extern "C" void kernel_launch(void* const* d_in, const int* in_sizes, int n_in,
                              void* d_out, int out_size, void* d_ws, size_t ws_size,
                              hipStream_t stream) {
    const float* trans = (const float*)d_in[0];
    const float* feats = (const float*)d_in[1];
    const int*   mask  = (const int*)d_in[2];
    const int*   tags  = (const int*)d_in[3];
    float*       out   = (float*)d_out;

    hipLaunchKernelGGL(zero_out_kernel, dim3(1), dim3(1), 0, stream, out);
    hipLaunchKernelGGL(forward_kernel, dim3(CRF_B), dim3(256), 0, stream,
                       trans, feats, mask, tags, out);
}

// Round 4
// 400.699 us; speedup vs baseline: 2.4624x; 1.6065x over previous
//
#include <hip/hip_runtime.h>

#define CRF_B 256
#define CRF_L 1024
#define CRF_T 128

typedef __attribute__((ext_vector_type(8)))  short bf16x8;
typedef __attribute__((ext_vector_type(16))) float f32x16;
typedef __attribute__((ext_vector_type(2)))  short short2v;

// raw barrier: LDS visibility only, NO vmcnt drain (global loads stay in flight)
#define WG_BARRIER() asm volatile("s_waitcnt lgkmcnt(0)\n\ts_barrier" ::: "memory")

__global__ void zero_out_kernel(float* out) { out[0] = 0.0f; }

static __device__ __forceinline__ unsigned short f2bf(float x) {
    union { float f; unsigned u; } v; v.f = x;
    unsigned r = v.u + 0x7FFFu + ((v.u >> 16) & 1u);   // RNE
    return (unsigned short)(r >> 16);
}

static __device__ __forceinline__ short2v bmax2(short2v a, short2v b) {
    return __builtin_elementwise_max(a, b);   // v_pk_max_i16; bf16>=0 is order-preserving
}
static __device__ __forceinline__ short2v fragmax(bf16x8 a) {
    short2v q0 = __builtin_shufflevector(a, a, 0, 1);
    short2v q1 = __builtin_shufflevector(a, a, 2, 3);
    short2v q2 = __builtin_shufflevector(a, a, 4, 5);
    short2v q3 = __builtin_shufflevector(a, a, 6, 7);
    return bmax2(bmax2(q0, q1), bmax2(q2, q3));
}

// One step of the linear-domain recurrence. x' = F * sig * (E . x_prev),
// kap += log(max x_prev). Writes x_prev (bf16) to s_e[SL] pre-barrier,
// reads A-fragments post-barrier. RR = prefetch register holding raw f[LV+1],
// reloaded with row LV+5 (consumed 4 steps later; no vmcnt drain at barriers).
#define STEP(LV, SL, RR) do {                                                 \
    if (h == 0) s_e[SL][j] = f2bf(x);                                         \
    WG_BARRIER();                                                             \
    bf16x8 A0_ = *(const bf16x8*)&s_e[SL][16 * 0 + 8 * h];                    \
    bf16x8 A1_ = *(const bf16x8*)&s_e[SL][16 * 1 + 8 * h];                    \
    bf16x8 A2_ = *(const bf16x8*)&s_e[SL][16 * 2 + 8 * h];                    \
    bf16x8 A3_ = *(const bf16x8*)&s_e[SL][16 * 3 + 8 * h];                    \
    bf16x8 A4_ = *(const bf16x8*)&s_e[SL][16 * 4 + 8 * h];                    \
    bf16x8 A5_ = *(const bf16x8*)&s_e[SL][16 * 5 + 8 * h];                    \
    bf16x8 A6_ = *(const bf16x8*)&s_e[SL][16 * 6 + 8 * h];                    \
    bf16x8 A7_ = *(const bf16x8*)&s_e[SL][16 * 7 + 8 * h];                    \
    f32x16 ac0 = __builtin_amdgcn_mfma_f32_32x32x16_bf16(A0_, Efrag[0], zacc, 0, 0, 0); \
    f32x16 ac1 = __builtin_amdgcn_mfma_f32_32x32x16_bf16(A1_, Efrag[1], zacc, 0, 0, 0); \
    f32x16 ac2 = __builtin_amdgcn_mfma_f32_32x32x16_bf16(A2_, Efrag[2], zacc, 0, 0, 0); \
    f32x16 ac3 = __builtin_amdgcn_mfma_f32_32x32x16_bf16(A3_, Efrag[3], zacc, 0, 0, 0); \
    ac0 = __builtin_amdgcn_mfma_f32_32x32x16_bf16(A4_, Efrag[4], ac0, 0, 0, 0); \
    ac1 = __builtin_amdgcn_mfma_f32_32x32x16_bf16(A5_, Efrag[5], ac1, 0, 0, 0); \
    ac2 = __builtin_amdgcn_mfma_f32_32x32x16_bf16(A6_, Efrag[6], ac2, 0, 0, 0); \
    ac3 = __builtin_amdgcn_mfma_f32_32x32x16_bf16(A7_, Efrag[7], ac3, 0, 0, 0); \
    short2v mx_ = bmax2(bmax2(bmax2(fragmax(A0_), fragmax(A1_)),              \
                              bmax2(fragmax(A2_), fragmax(A3_))),             \
                        bmax2(bmax2(fragmax(A4_), fragmax(A5_)),              \
                              bmax2(fragmax(A6_), fragmax(A7_))));            \
    unsigned mu_ = __builtin_bit_cast(unsigned, mx_);                         \
    float nrm = fmaxf(__builtin_bit_cast(float, mu_ << 16),                   \
                      __builtin_bit_cast(float, mu_ & 0xFFFF0000u));          \
    nrm = fmaxf(nrm, __shfl_xor(nrm, 32, 64));                                \
    float sig_ = __builtin_amdgcn_rcpf(nrm);                                  \
    kap += __logf(nrm);                                                       \
    float Fn_ = __expf(RR);                                                   \
    { int ld_ = (LV) + 5; if (ld_ > CRF_L - 1) ld_ = CRF_L - 1;               \
      RR = fb[(size_t)ld_ * CRF_T + j]; }                                     \
    float sres_ = (ac0[0] + ac1[0]) + (ac2[0] + ac3[0]);                      \
    x = (F * sig_) * sres_;                                                   \
    F = Fn_;                                                                  \
} while (0)

// One workgroup (256 threads = 4 waves) per batch. Wave w owns cols
// [32w,32w+32). Recurrence kept in LINEAR domain: x_j = exp(p_j - kap).
// Matvec via v_mfma_f32_32x32x16_bf16 with broadcast-A (validated layout:
// all A-rows = x, so every lane's acc[0] = result for col lane&31).
__global__ __launch_bounds__(256) void forward_kernel(
    const float* __restrict__ trans, const float* __restrict__ feats,
    const int* __restrict__ mask, const int* __restrict__ tags,
    float* __restrict__ out)
{
    const int b    = blockIdx.x;
    const int t    = threadIdx.x;
    const int w    = t >> 6;
    const int lane = t & 63;
    const int h    = lane >> 5;
    const int j    = w * 32 + (lane & 31);

    __shared__ __align__(16) unsigned short s_e[2][CRF_T];  // bf16 x, parity dbuf
    __shared__ float s_p0[CRF_T];
    __shared__ float s_fin[4];
    __shared__ float s_gold;
    __shared__ int   s_len;

    if (t == 0) { s_len = 0; s_gold = 0.0f; }
    __syncthreads();

    // ---- per-batch length + gold score (single merged pass) ----
    {
        int cnt = 0; float gsum = 0.0f;
        const int base = b * CRF_L;
        for (int l = t; l < CRF_L; l += 256) {
            if (mask[base + l] != 0) {
                cnt++;
                int tg = tags[base + l];
                float gv = feats[(size_t)(base + l) * CRF_T + tg];
                if (l > 0) gv += trans[tags[base + l - 1] * CRF_T + tg];
                gsum += gv;
            }
        }
        for (int off = 32; off > 0; off >>= 1) {
            cnt  += __shfl_down(cnt, off, 64);
            gsum += __shfl_down(gsum, off, 64);
        }
        if (lane == 0) { atomicAdd(&s_len, cnt); atomicAdd(&s_gold, gsum); }
    }

    // ---- E = exp(trans) as bf16 B-fragments (one-time; validated k-map) ----
    bf16x8 Efrag[8];
#pragma unroll
    for (int kt = 0; kt < 8; ++kt) {
#pragma unroll
        for (int e = 0; e < 8; ++e) {
            int k = 16 * kt + 8 * h + e;
            Efrag[kt][e] = (short)f2bf(__expf(trans[k * CRF_T + j]));
        }
    }

    const float* fb = feats + (size_t)b * CRF_L * CRF_T;

    // ---- init: x0 = exp(p0 - m0), kap = m0 (m0 computed identically by all) ----
    float p0 = fb[j];
    if (h == 0) s_p0[j] = p0;
    __syncthreads();
    const int len = s_len;
    float m0 = s_p0[0];
#pragma unroll 16
    for (int k = 1; k < CRF_T; ++k) m0 = fmaxf(m0, s_p0[k]);
    float x   = __expf(p0 - m0);
    float kap = m0;

    const f32x16 zacc = {};

    // F pipeline: F = exp(f_l) for the step about to run; r0..r3 = raw rows l+1..l+4
    float F   = __expf(fb[(size_t)1 * CRF_T + j]);
    float r0f = fb[(size_t)2 * CRF_T + j];
    float r1f = fb[(size_t)3 * CRF_T + j];
    float r2f = fb[(size_t)4 * CRF_T + j];
    float r3f = fb[(size_t)5 * CRF_T + j];

    const int lim = 1 + ((len - 1) & ~3);   // lim odd; phases have static parity
    for (int l = 1; l < lim; l += 4) {
        STEP(l,     1, r0f);
        STEP(l + 1, 0, r1f);
        STEP(l + 2, 1, r2f);
        STEP(l + 3, 0, r3f);
    }
    if (lim + 0 < len) STEP(lim + 0, 1, r0f);
    if (lim + 1 < len) STEP(lim + 1, 0, r1f);
    if (lim + 2 < len) STEP(lim + 2, 1, r2f);

    // ---- final: forward = kap + log(sum_j x_j) ----
    {
        float v = (h == 0) ? x : 0.0f;
        v += __shfl_xor(v, 1, 64);
        v += __shfl_xor(v, 2, 64);
        v += __shfl_xor(v, 4, 64);
        v += __shfl_xor(v, 8, 64);
        v += __shfl_xor(v, 16, 64);
        v += __shfl_xor(v, 32, 64);
        if (lane == 0) s_fin[w] = v;
        __syncthreads();
        if (t == 0) {
            float tot = s_fin[0] + s_fin[1] + s_fin[2] + s_fin[3];
            atomicAdd(out, kap + __logf(tot) - s_gold);
        }
    }
}

extern "C" void kernel_launch(void* const* d_in, const int* in_sizes, int n_in,
                              void* d_out, int out_size, void* d_ws, size_t ws_size,
                              hipStream_t stream) {
    const float* trans = (const float*)d_in[0];
    const float* feats = (const float*)d_in[1];
    const int*   mask  = (const int*)d_in[2];
    const int*   tags  = (const int*)d_in[3];
    float*       out   = (float*)d_out;

    hipLaunchKernelGGL(zero_out_kernel, dim3(1), dim3(1), 0, stream, out);
    hipLaunchKernelGGL(forward_kernel, dim3(CRF_B), dim3(256), 0, stream,
                       trans, feats, mask, tags, out);
}